// Round 8
// baseline (306.361 us; speedup 1.0000x reference)
//
#include <hip/hip_runtime.h>
#include <cstdint>
#include <cstddef>

typedef __attribute__((ext_vector_type(8))) short short8;
typedef __attribute__((ext_vector_type(4))) float f4;
typedef __attribute__((ext_vector_type(4))) unsigned int u4;

static __device__ __forceinline__ unsigned short f2bf(float x) {
  unsigned int u = __float_as_uint(x);
  unsigned int r = (u + 0x7FFFu + ((u >> 16) & 1u)) >> 16;  // RNE
  return (unsigned short)r;
}

// async global->LDS, 16B per lane, wave-uniform LDS base + lane*16
static __device__ __forceinline__ void gll16(const unsigned short* g, unsigned short* l) {
  __builtin_amdgcn_global_load_lds(
      (const __attribute__((address_space(1))) unsigned int*)g,
      (__attribute__((address_space(3))) unsigned int*)l, 16, 0, 0);
}

template <int N>
static __device__ __forceinline__ void wait_vmcnt() {
  if constexpr (N == 0) asm volatile("s_waitcnt vmcnt(0)" ::: "memory");
  else if constexpr (N == 1) asm volatile("s_waitcnt vmcnt(1)" ::: "memory");
  else if constexpr (N == 2) asm volatile("s_waitcnt vmcnt(2)" ::: "memory");
  else if constexpr (N == 3) asm volatile("s_waitcnt vmcnt(3)" ::: "memory");
  else if constexpr (N == 4) asm volatile("s_waitcnt vmcnt(4)" ::: "memory");
  // N < 0: no wait
}

// ---------------- transpose tile helper: dst[n][k] = src[k][n], one 64x64 tile ------
static __device__ __forceinline__ void trans_tile(
    const float* __restrict__ src, unsigned short* __restrict__ dst,
    int R, int C, int c0, int r0, int tid, unsigned short* tile) {
#pragma unroll
  for (int s = 0; s < 2; ++s) {
    int chunk = tid + s * 256;
    int c8 = chunk & 7, r = chunk >> 3;
    const float* p = src + (size_t)(r0 + r) * C + c0 + c8 * 8;
    f4 a = *(const f4*)p;
    f4 b = *(const f4*)(p + 4);
    union { unsigned short u[8]; u4 v; } pk;
#pragma unroll
    for (int i = 0; i < 4; ++i) { pk.u[i] = f2bf(a[i]); pk.u[4 + i] = f2bf(b[i]); }
    *(u4*)(tile + r * 72 + c8 * 8) = pk.v;
  }
  __syncthreads();
#pragma unroll
  for (int s = 0; s < 2; ++s) {
    int chunk = tid + s * 256;
    int r8 = chunk & 7, c = chunk >> 3;
    union { unsigned short u[8]; u4 v; } pk;
#pragma unroll
    for (int i = 0; i < 8; ++i) pk.u[i] = tile[(r8 * 8 + i) * 72 + c];
    *(u4*)(dst + (size_t)(c0 + c) * R + r0 + r8 * 8) = pk.v;
  }
}

// ---------------- fused prep: x->bf16 cvt + wq/wk/wv transposes (1 launch) ----------
__global__ __launch_bounds__(256) void k_prep(
    const float* __restrict__ x, const float* __restrict__ wq,
    const float* __restrict__ wk, const float* __restrict__ wv,
    unsigned short* __restrict__ Xb, unsigned short* __restrict__ WqkvT) {
  __shared__ alignas(16) unsigned short tile[64 * 72];
  int bid = blockIdx.x;
  int tid = threadIdx.x;
  if (bid < 4096) {  // cvt: 8 f32 per thread
    int gid = bid * 256 + tid;
    const float* p = x + (size_t)gid * 8;
    f4 a = *(const f4*)p;
    f4 b = *(const f4*)(p + 4);
    union { unsigned short u[8]; u4 v; } pk;
#pragma unroll
    for (int i = 0; i < 4; ++i) { pk.u[i] = f2bf(a[i]); pk.u[4 + i] = f2bf(b[i]); }
    *(u4*)(Xb + (size_t)gid * 8) = pk.v;
  } else if (bid < 4096 + 1024) {  // wq transpose (32x32 tiles)
    int idx = bid - 4096;
    trans_tile(wq, WqkvT, 2048, 2048, (idx & 31) * 64, (idx >> 5) * 64, tid, tile);
  } else if (bid < 4096 + 1024 + 256) {  // wk (8x32 tiles)
    int idx = bid - (4096 + 1024);
    trans_tile(wk, WqkvT + (size_t)2048 * 2048, 2048, 512,
               (idx & 7) * 64, (idx >> 3) * 64, tid, tile);
  } else {  // wv
    int idx = bid - (4096 + 1024 + 256);
    trans_tile(wv, WqkvT + (size_t)2560 * 2048, 2048, 512,
               (idx & 7) * 64, (idx >> 3) * 64, tid, tile);
  }
}

// ---------------- standalone transpose (wo, runs after attn frees ws) ----------------
__global__ __launch_bounds__(256) void k_transpose_f(
    const float* __restrict__ src, unsigned short* __restrict__ dst, int R, int C) {
  __shared__ alignas(16) unsigned short tile[64 * 72];
  trans_tile(src, dst, R, C, blockIdx.x * 64, blockIdx.y * 64, threadIdx.x, tile);
}

// ================= 8-wave phase-split GEMM: C[M,N] = A[M,K] @ Bt[N,K]^T =================
#define PHASE(QM, QN, WAITC, ...)                                              \
  {                                                                            \
    wait_vmcnt<WAITC>();                                                       \
    __builtin_amdgcn_s_barrier();                                              \
    asm volatile("" ::: "memory");                                             \
    short8 af[FI][2], bf[2][2];                                                \
    _Pragma("unroll") for (int i = 0; i < FI; ++i)                             \
      _Pragma("unroll") for (int ks = 0; ks < 2; ++ks)                         \
        af[i][ks] = *(const short8*)(&As[cur][((QM) * (BM / 2) + wm * (BM / 4) + i * 16 + l16) * 64 + kswz[ks]]); \
    _Pragma("unroll") for (int j = 0; j < 2; ++j)                              \
      _Pragma("unroll") for (int ks = 0; ks < 2; ++ks)                         \
        bf[j][ks] = *(const short8*)(&Bs[cur][((QN) * 128 + wn * 32 + j * 16 + l16) * 64 + kswz[ks]]); \
    __VA_ARGS__                                                                \
    __builtin_amdgcn_s_setprio(1);                                             \
    _Pragma("unroll") for (int i = 0; i < FI; ++i)                             \
      _Pragma("unroll") for (int j = 0; j < 2; ++j)                            \
        _Pragma("unroll") for (int ks = 0; ks < 2; ++ks)                       \
          acc[(QM) * FI + i][(QN) * 2 + j] = __builtin_amdgcn_mfma_f32_16x16x32_bf16( \
              af[i][ks], bf[j][ks], acc[(QM) * FI + i][(QN) * 2 + j], 0, 0, 0); \
    __builtin_amdgcn_s_setprio(0);                                             \
  }

template <int BM, bool BF16OUT>
__global__ __launch_bounds__(512, 2) void k_gemm8(
    const unsigned short* __restrict__ A, const unsigned short* __restrict__ Bt,
    void* __restrict__ Cout, int M, int N, int K) {
  constexpr int CA = BM / 128;  // gll16 calls per A half-region
  constexpr int FI = BM / 64;   // A fragments per phase per wave
  constexpr int WA = 2 + CA, WB = 2 * CA, WC = CA + 2, PB = CA;
  __shared__ alignas(16) unsigned short As[2][BM * 64];
  __shared__ alignas(16) unsigned short Bs[2][256 * 64];
  (void)M;

  int tid = threadIdx.x;
  int wid = tid >> 6, lane = tid & 63, quad = lane >> 4, l16 = lane & 15;
  int wm = wid >> 2, wn = wid & 3;

  int nx = gridDim.x;
  int id = blockIdx.y * nx + blockIdx.x;
  int nwg = nx * gridDim.y;
  int per = nwg >> 3;
  int lin = (id & 7) * per + (id >> 3);
  int bx = lin % nx, by = lin / nx;
  int bm = by * BM, bn = bx * 256;

  int srow = lane >> 3;
  int scol = ((lane & 7) ^ srow) << 3;  // shorts
  const unsigned short* Ast = A + (size_t)(bm + wid * 8 + srow) * K + scol;
  const unsigned short* Bst = Bt + (size_t)(bn + wid * 8 + srow) * K + scol;
  const int ldsw = wid * 512;

  int kswz[2];
#pragma unroll
  for (int ks = 0; ks < 2; ++ks) kswz[ks] = (ks * 32 + quad * 8) ^ ((l16 & 7) << 3);

  f4 zero = {0.f, 0.f, 0.f, 0.f};
  f4 acc[2 * FI][4];
#pragma unroll
  for (int i = 0; i < 2 * FI; ++i)
#pragma unroll
    for (int j = 0; j < 4; ++j) acc[i][j] = zero;

  if constexpr (CA == 2) {
    gll16(Ast, &As[0][ldsw]);
    gll16(Ast + (size_t)64 * K, &As[0][ldsw + 64 * 64]);
  } else {
    gll16(Ast, &As[0][ldsw]);
  }
  gll16(Bst, &Bs[0][ldsw]);
  gll16(Bst + (size_t)64 * K, &Bs[0][ldsw + 64 * 64]);
  gll16(Bst + (size_t)128 * K, &Bs[0][ldsw + 128 * 64]);
  gll16(Bst + (size_t)192 * K, &Bs[0][ldsw + 192 * 64]);
  if constexpr (CA == 2) {
    gll16(Ast + (size_t)128 * K, &As[0][ldsw + 128 * 64]);
    gll16(Ast + (size_t)192 * K, &As[0][ldsw + 192 * 64]);
  } else {
    gll16(Ast + (size_t)64 * K, &As[0][ldsw + 64 * 64]);
  }

  int nt = K >> 6;
  int cur = 0;
  for (int t = 0; t < nt - 1; ++t) {
    int k0n = (t + 1) << 6;
    int nxt = cur ^ 1;
    unsigned short* Asn = &As[nxt][0];
    unsigned short* Bsn = &Bs[nxt][0];
    PHASE(0, 0, WA,
      if constexpr (CA == 2) {
        gll16(Ast + k0n, Asn + ldsw);
        gll16(Ast + (size_t)64 * K + k0n, Asn + ldsw + 64 * 64);
      } else {
        gll16(Ast + k0n, Asn + ldsw);
      })
    PHASE(0, 1, WB,
      gll16(Bst + k0n, Bsn + ldsw);
      gll16(Bst + (size_t)64 * K + k0n, Bsn + ldsw + 64 * 64);)
    PHASE(1, 0, WC,
      gll16(Bst + (size_t)128 * K + k0n, Bsn + ldsw + 128 * 64);
      gll16(Bst + (size_t)192 * K + k0n, Bsn + ldsw + 192 * 64);)
    PHASE(1, 1, -1,
      if constexpr (CA == 2) {
        gll16(Ast + (size_t)128 * K + k0n, Asn + ldsw + 128 * 64);
        gll16(Ast + (size_t)192 * K + k0n, Asn + ldsw + 192 * 64);
      } else {
        gll16(Ast + (size_t)64 * K + k0n, Asn + ldsw + 64 * 64);
      })
    cur = nxt;
  }
  PHASE(0, 0, WA, ;)
  PHASE(0, 1, PB, ;)
  PHASE(1, 0, 0, ;)
  PHASE(1, 1, -1, ;)

#pragma unroll
  for (int mi = 0; mi < 2 * FI; ++mi) {
    int row = bm + (mi / FI) * (BM / 2) + wm * (BM / 4) + (mi % FI) * 16 + quad * 4;
#pragma unroll
    for (int nj = 0; nj < 4; ++nj) {
      int col = bn + (nj >> 1) * 128 + wn * 32 + (nj & 1) * 16 + l16;
#pragma unroll
      for (int r = 0; r < 4; ++r) {
        if constexpr (BF16OUT)
          ((unsigned short*)Cout)[(size_t)(row + r) * N + col] = f2bf(acc[mi][nj][r]);
        else
          ((float*)Cout)[(size_t)(row + r) * N + col] = acc[mi][nj][r];
      }
    }
  }
}

// ---------------- fused RoPE (K only) + V transpose (1 launch) ----------------
// Q is now roped inside k_attn (each Q row loaded exactly once there).
__global__ __launch_bounds__(256) void k_ropev(
    unsigned short* __restrict__ QKV, unsigned short* __restrict__ VT) {
  __shared__ alignas(16) unsigned short tile[64 * 72];
  int bid = blockIdx.x;
  int tid = threadIdx.x;
  if (bid < 512) {  // RoPE on K (4 heads), 8 d-pairs/thread
    int gid = bid * 256 + tid;
    int c8 = gid & 7; int g = gid >> 3;
    int h4 = g & 3; g >>= 2;
    int t = g & 2047; int b = g >> 11;
    size_t p = (size_t)(b * 2048 + t) * 3072 + 2048 + h4 * 128 + c8 * 8;
    short8 x0 = *(const short8*)(QKV + p);
    short8 x1 = *(const short8*)(QKV + p + 64);
    short8 o0, o1;
    float tf = (float)t;
#pragma unroll
    for (int i = 0; i < 8; ++i) {
      int d = c8 * 8 + i;
      float a0 = __uint_as_float((unsigned int)(unsigned short)x0[i] << 16);
      float a1 = __uint_as_float((unsigned int)(unsigned short)x1[i] << 16);
      float freq = exp2f(-(float)d * 0.20762050593046f);  // log2(10000)/64
      float ang = tf * freq;
      float cv = __cosf(ang), sv = __sinf(ang);
      o0[i] = (short)f2bf(a0 * cv - a1 * sv);
      o1[i] = (short)f2bf(a1 * cv + a0 * sv);
    }
    *(short8*)(QKV + p) = o0;
    *(short8*)(QKV + p + 64) = o1;
  } else {  // V transpose (reads V region only)
    int idx = bid - 512;            // 512 blocks
    int t0 = (idx & 31) * 64;
    int g = idx >> 5;               // b*8 + hk*2 + dh
    int dh = g & 1, hk = (g >> 1) & 3, b = g >> 3;
    int d0 = dh * 64;
    const unsigned short* src = QKV + (size_t)(b * 2048 + t0) * 3072 + 2560 + hk * 128 + d0;
#pragma unroll
    for (int s = 0; s < 2; ++s) {
      int chunk = tid + s * 256;
      int c8 = chunk & 7, r = chunk >> 3;
      *(u4*)(tile + r * 72 + c8 * 8) = *(const u4*)(src + (size_t)r * 3072 + c8 * 8);
    }
    __syncthreads();
    unsigned short* dst = VT + ((size_t)((b * 4 + hk) * 128 + d0)) * 2048 + t0;
#pragma unroll
    for (int s = 0; s < 2; ++s) {
      int chunk = tid + s * 256;
      int r8 = chunk & 7, c = chunk >> 3;
      union { unsigned short u[8]; u4 v; } pk;
#pragma unroll
      for (int i = 0; i < 8; ++i) pk.u[i] = tile[(r8 * 8 + i) * 72 + c];
      *(u4*)(dst + (size_t)c * 2048 + r8 * 8) = pk.v;
    }
  }
}

// ---------------- softmax + P->bf16 pack (per 16q x 64k score tile) ----------------
static __device__ __forceinline__ void softmax_pack(
    f4* st, f4* o, float& m, float& l,
    int quad, int l16, int qrow, int K0, bool mask, bool odd, short8* pb) {
  if (mask) {
#pragma unroll
    for (int kt = 0; kt < 4; ++kt)
#pragma unroll
      for (int r = 0; r < 4; ++r)
        if (K0 + kt * 16 + quad * 4 + r > qrow) st[kt][r] = -1e30f;
  }
  float sm = -1e30f;
#pragma unroll
  for (int kt = 0; kt < 4; ++kt)
#pragma unroll
    for (int r = 0; r < 4; ++r) sm = fmaxf(sm, st[kt][r]);
  sm = fmaxf(sm, __shfl_xor(sm, 16));
  sm = fmaxf(sm, __shfl_xor(sm, 32));
  // defer-max (T13): only raise m when the tile max grew past m+8.
  bool grow = !__all(sm - m <= 8.f);
  float mnew = grow ? fmaxf(m, sm) : m;
  f4 pv[4];
  float rs = 0.f;
#pragma unroll
  for (int kt = 0; kt < 4; ++kt)
#pragma unroll
    for (int r = 0; r < 4; ++r) {
      pv[kt][r] = __expf(st[kt][r] - mnew);
      rs += pv[kt][r];
    }
  rs += __shfl_xor(rs, 16);
  rs += __shfl_xor(rs, 32);
  if (grow) {
    float alpha = __expf(m - mnew);
    l = l * alpha + rs;
    m = mnew;
#pragma unroll
    for (int i = 0; i < 8; ++i) o[i] *= alpha;
  } else {
    l += rs;
  }
  unsigned int c[4][2];
#pragma unroll
  for (int kt = 0; kt < 4; ++kt)
#pragma unroll
    for (int p = 0; p < 2; ++p)
      asm("v_cvt_pk_bf16_f32 %0, %1, %2"
          : "=v"(c[kt][p]) : "v"(pv[kt][2 * p]), "v"(pv[kt][2 * p + 1]));
#pragma unroll
  for (int kh = 0; kh < 2; ++kh) {
    unsigned int A0 = c[2 * kh][0], A1 = c[2 * kh][1];
    unsigned int B0 = c[2 * kh + 1][0], B1 = c[2 * kh + 1][1];
    asm("v_permlane32_swap_b32 %0, %1" : "+v"(A0), "+v"(B0));
    asm("v_permlane32_swap_b32 %0, %1" : "+v"(A1), "+v"(B1));
    unsigned int tA0 = (unsigned int)__builtin_amdgcn_ds_swizzle((int)A0, 0x401F);
    unsigned int tA1 = (unsigned int)__builtin_amdgcn_ds_swizzle((int)A1, 0x401F);
    unsigned int tB0 = (unsigned int)__builtin_amdgcn_ds_swizzle((int)B0, 0x401F);
    unsigned int tB1 = (unsigned int)__builtin_amdgcn_ds_swizzle((int)B1, 0x401F);
    union { unsigned int u[4]; short8 s; } pk;
    pk.u[0] = odd ? tB0 : A0;
    pk.u[1] = odd ? tB1 : A1;
    pk.u[2] = odd ? B0 : tA0;
    pk.u[3] = odd ? B1 : tA1;
    pb[kh] = pk.s;
  }
}

// ---------------- QK^T + softmax + pack for one 16q x 64k tile ----------------
static __device__ __forceinline__ void qk_softmax(
    const unsigned short* __restrict__ Ks, const short8* qf, f4* o, float& m, float& l,
    int quad, int l16, int qrow, int K0, bool mask, bool odd, short8* pb) {
  f4 zero = {0.f, 0.f, 0.f, 0.f};
  f4 st[4];
  __builtin_amdgcn_s_setprio(1);  // T5
#pragma unroll
  for (int kt = 0; kt < 4; ++kt) {
    st[kt] = zero;
#pragma unroll
    for (int ks = 0; ks < 4; ++ks) {
      short8 kf = *(const short8*)(Ks + (kt * 16 + l16) * 136 + ks * 32 + quad * 8);
      st[kt] = __builtin_amdgcn_mfma_f32_16x16x32_bf16(kf, qf[ks], st[kt], 0, 0, 0);
    }
  }
  __builtin_amdgcn_s_setprio(0);
  softmax_pack(st, o, m, l, quad, l16, qrow, K0, mask, odd, pb);
}

// ---------------- PV: single accumulator ----------------
static __device__ __forceinline__ void pv_step(
    const unsigned short* __restrict__ Vs, const short8* pb, f4* o, int quad, int l16) {
  __builtin_amdgcn_s_setprio(1);  // T5
#pragma unroll
  for (int kh = 0; kh < 2; ++kh)
#pragma unroll
    for (int i = 0; i < 8; ++i) {
      short8 vf = *(const short8*)(Vs + (i * 16 + l16) * 72 + kh * 32 + quad * 8);
      o[i] = __builtin_amdgcn_mfma_f32_16x16x32_bf16(vf, pb[kh], o[i], 0, 0, 0);
    }
  __builtin_amdgcn_s_setprio(0);
}

// ---------------- PV: dual accumulators share one pass of V reads ----------------
static __device__ __forceinline__ void pv_step2(
    const unsigned short* __restrict__ Vs, const short8* pbA, const short8* pbB,
    f4* oA, f4* oB, int quad, int l16) {
  __builtin_amdgcn_s_setprio(1);  // T5
#pragma unroll
  for (int kh = 0; kh < 2; ++kh)
#pragma unroll
    for (int i = 0; i < 8; ++i) {
      short8 vf = *(const short8*)(Vs + (i * 16 + l16) * 72 + kh * 32 + quad * 8);
      oA[i] = __builtin_amdgcn_mfma_f32_16x16x32_bf16(vf, pbA[kh], oA[i], 0, 0, 0);
      oB[i] = __builtin_amdgcn_mfma_f32_16x16x32_bf16(vf, pbB[kh], oB[i], 0, 0, 0);
    }
  __builtin_amdgcn_s_setprio(0);
}

// ---------------- Flash attention, paired q-tiles + double-buffered staging ----------------
// Q is roped in-register here (pairs d,d+64 live in the same lane: qf[ks] vs qf[ks+2]).
__global__ __launch_bounds__(256, 2) void k_attn(
    const unsigned short* __restrict__ QKV,  // [B*T,3072], Q raw, K roped
    const unsigned short* __restrict__ VT,   // [B,4,128,T]
    unsigned short* __restrict__ Y) {        // [B*T,2048]
  __shared__ alignas(16) unsigned short Ks[2][64 * 136];   // 64 keys x 128 d
  __shared__ alignas(16) unsigned short Vs[2][128 * 72];   // 128 d x 64 keys
  int tid = threadIdx.x;
  int w = tid >> 6, lane = tid & 63, quad = lane >> 4, l16 = lane & 15;
  bool odd = (quad & 1) != 0;
  int bh = blockIdx.y; int b = bh >> 4, h = bh & 15, hk = h >> 2;
  int v = blockIdx.x;                 // 0..15
  int q0A = v * 64 + w * 16;          // early tile
  int q0B = (31 - v) * 64 + w * 16;   // late tile
  const unsigned short* Qh = QKV + (size_t)b * 2048 * 3072 + h * 128;
  const unsigned short* Kh = QKV + (size_t)b * 2048 * 3072 + 2048 + hk * 128;
  const unsigned short* Vh = VT + ((size_t)(b * 4 + hk) * 128) * 2048;

  int rK0 = tid >> 4, cK = tid & 15;
  int rV0 = tid >> 3, cV = tid & 7;

  short8 qfA[4], qfB[4];
#pragma unroll
  for (int ks = 0; ks < 4; ++ks) {
    qfA[ks] = *(const short8*)(Qh + (size_t)(q0A + l16) * 3072 + ks * 32 + quad * 8);
    qfB[ks] = *(const short8*)(Qh + (size_t)(q0B + l16) * 3072 + ks * 32 + quad * 8);
  }
  // in-register Q RoPE + 1/sqrt(128) scale; qf[ks][i] holds d = ks*32+quad*8+i,
  // partner d+64 is qf[ks+2][i] (same lane).
#pragma unroll
  for (int tix = 0; tix < 2; ++tix) {
    short8* qf = tix ? qfB : qfA;
    float tf = (float)((tix ? q0B : q0A) + l16);
#pragma unroll
    for (int ks = 0; ks < 2; ++ks)
#pragma unroll
      for (int i = 0; i < 8; ++i) {
        int d = ks * 32 + quad * 8 + i;
        float x0 = __uint_as_float((unsigned int)(unsigned short)qf[ks][i] << 16);
        float x1 = __uint_as_float((unsigned int)(unsigned short)qf[ks + 2][i] << 16);
        float freq = exp2f(-(float)d * 0.20762050593046f);  // log2(10000)/64
        float ang = tf * freq;
        float cv = __cosf(ang), sv = __sinf(ang);
        qf[ks][i] = (short)f2bf((x0 * cv - x1 * sv) * 0.088388347648318f);
        qf[ks + 2][i] = (short)f2bf((x1 * cv + x0 * sv) * 0.088388347648318f);
      }
  }

  f4 zero = {0.f, 0.f, 0.f, 0.f};
  f4 oA[8], oB[8];
#pragma unroll
  for (int i = 0; i < 8; ++i) { oA[i] = zero; oB[i] = zero; }
  float mA = -1e30f, lA = 0.f, mB = -1e30f, lB = 0.f;

  int nch = 32 - v;  // chunks 0..31-v (tile B's causal range)

#pragma unroll
  for (int s = 0; s < 4; ++s) {
    int rK = rK0 + 16 * s;
    *(u4*)(&Ks[0][0] + rK * 136 + cK * 8) =
        *(const u4*)(Kh + (size_t)rK * 3072 + cK * 8);
    int rV = rV0 + 32 * s;
    *(u4*)(&Vs[0][0] + rV * 72 + cV * 8) =
        *(const u4*)(Vh + (size_t)rV * 2048 + cV * 8);
  }
  __syncthreads();

  for (int kc = 0; kc < nch; ++kc) {
    int cur = kc & 1, nxt = cur ^ 1;
    int K0 = kc * 64;
    bool have_next = (kc + 1) < nch;
    u4 kreg[4], vreg[4];
    if (have_next) {  // issue next-chunk loads before compute
      int K0n = K0 + 64;
#pragma unroll
      for (int s = 0; s < 4; ++s) {
        int rK = rK0 + 16 * s;
        kreg[s] = *(const u4*)(Kh + (size_t)(K0n + rK) * 3072 + cK * 8);
        int rV = rV0 + 32 * s;
        vreg[s] = *(const u4*)(Vh + (size_t)rV * 2048 + K0n + cV * 8);
      }
    }

    if (kc <= v) {  // dual iteration: share V reads across both q-tiles
      short8 pbA[2], pbB[2];
      qk_softmax(&Ks[cur][0], qfA, oA, mA, lA, quad, l16, q0A + l16, K0, kc == v, odd, pbA);
      qk_softmax(&Ks[cur][0], qfB, oB, mB, lB, quad, l16, q0B + l16, K0, false, odd, pbB);
      pv_step2(&Vs[cur][0], pbA, pbB, oA, oB, quad, l16);
    } else {
      short8 pb[2];
      qk_softmax(&Ks[cur][0], qfB, oB, mB, lB, quad, l16, q0B + l16, K0, kc == nch - 1, odd, pb);
      pv_step(&Vs[cur][0], pb, oB, quad, l16);
    }

    if (have_next) {  // vmcnt drain lands here, off the critical path
#pragma unroll
      for (int s = 0; s < 4; ++s) {
        int rK = rK0 + 16 * s;
        *(u4*)(&Ks[nxt][0] + rK * 136 + cK * 8) = kreg[s];
        int rV = rV0 + 32 * s;
        *(u4*)(&Vs[nxt][0] + rV * 72 + cV * 8) = vreg[s];
      }
    }
    __syncthreads();
  }

  float rA = 1.f / lA, rB = 1.f / lB;
  size_t yrowA = (size_t)(b * 2048 + q0A + l16) * 2048 + h * 128;
  size_t yrowB = (size_t)(b * 2048 + q0B + l16) * 2048 + h * 128;
#pragma unroll
  for (int i = 0; i < 8; ++i)
#pragma unroll
    for (int r = 0; r < 4; ++r) {
      Y[yrowA + i * 16 + quad * 4 + r] = f2bf(oA[i][r] * rA);
      Y[yrowB + i * 16 + quad * 4 + r] = f2bf(oB[i][r] * rB);
    }
}

extern "C" void kernel_launch(void* const* d_in, const int* in_sizes, int n_in,
                              void* d_out, int out_size, void* d_ws, size_t ws_size,
                              hipStream_t stream) {
  const float* x  = (const float*)d_in[0];   // [2,2048,2048] fp32
  const float* wq = (const float*)d_in[1];   // [2048,2048]
  const float* wk = (const float*)d_in[2];   // [2048,512]
  const float* wv = (const float*)d_in[3];   // [2048,512]
  const float* wo = (const float*)d_in[4];   // [2048,2048]
  float* outp = (float*)d_out;               // [2,2048,2048] fp32

  unsigned short* WqkvT = (unsigned short*)d_out;
  unsigned short* VT    = WqkvT + (size_t)3072 * 2048;
  unsigned short* Xb    = VT + (size_t)2 * 4 * 128 * 2048;
  unsigned short* QKV = (unsigned short*)d_ws;               // [4096][3072]
  unsigned short* Yb  = QKV + (size_t)4096 * 3072;           // [4096][2048]
  unsigned short* WoT = QKV;

  dim3 blk(256);
  k_prep<<<dim3(5632), blk, 0, stream>>>(x, wq, wk, wv, Xb, WqkvT);

  k_gemm8<256, true><<<dim3(12, 16), dim3(512), 0, stream>>>(
      Xb, WqkvT, QKV, 4096, 3072, 2048);

  k_ropev<<<dim3(1024), blk, 0, stream>>>(QKV, VT);

  k_attn<<<dim3(16, 32), blk, 0, stream>>>(QKV, VT, Yb);

  k_transpose_f<<<dim3(32, 32), blk, 0, stream>>>(wo, WoT, 2048, 2048);
  k_gemm8<128, false><<<dim3(8, 32), dim3(512), 0, stream>>>(
      Yb, WoT, outp, 4096, 2048, 2048);
}

// Round 9
// 294.389 us; speedup vs baseline: 1.0407x; 1.0407x over previous
//
#include <hip/hip_runtime.h>
#include <cstdint>
#include <cstddef>

typedef __attribute__((ext_vector_type(8))) short short8;
typedef __attribute__((ext_vector_type(4))) float f4;
typedef __attribute__((ext_vector_type(4))) unsigned int u4;

static __device__ __forceinline__ unsigned short f2bf(float x) {
  unsigned int u = __float_as_uint(x);
  unsigned int r = (u + 0x7FFFu + ((u >> 16) & 1u)) >> 16;  // RNE
  return (unsigned short)r;
}

// async global->LDS, 16B per lane, wave-uniform LDS base + lane*16
static __device__ __forceinline__ void gll16(const unsigned short* g, unsigned short* l) {
  __builtin_amdgcn_global_load_lds(
      (const __attribute__((address_space(1))) unsigned int*)g,
      (__attribute__((address_space(3))) unsigned int*)l, 16, 0, 0);
}

template <int N>
static __device__ __forceinline__ void wait_vmcnt() {
  if constexpr (N == 0) asm volatile("s_waitcnt vmcnt(0)" ::: "memory");
  else if constexpr (N == 1) asm volatile("s_waitcnt vmcnt(1)" ::: "memory");
  else if constexpr (N == 2) asm volatile("s_waitcnt vmcnt(2)" ::: "memory");
  else if constexpr (N == 3) asm volatile("s_waitcnt vmcnt(3)" ::: "memory");
  else if constexpr (N == 4) asm volatile("s_waitcnt vmcnt(4)" ::: "memory");
  // N < 0: no wait
}

// ---------------- transpose tile helper: dst[n][k] = src[k][n], one 64x64 tile ------
static __device__ __forceinline__ void trans_tile(
    const float* __restrict__ src, unsigned short* __restrict__ dst,
    int R, int C, int c0, int r0, int tid, unsigned short* tile) {
#pragma unroll
  for (int s = 0; s < 2; ++s) {
    int chunk = tid + s * 256;
    int c8 = chunk & 7, r = chunk >> 3;
    const float* p = src + (size_t)(r0 + r) * C + c0 + c8 * 8;
    f4 a = *(const f4*)p;
    f4 b = *(const f4*)(p + 4);
    union { unsigned short u[8]; u4 v; } pk;
#pragma unroll
    for (int i = 0; i < 4; ++i) { pk.u[i] = f2bf(a[i]); pk.u[4 + i] = f2bf(b[i]); }
    *(u4*)(tile + r * 72 + c8 * 8) = pk.v;
  }
  __syncthreads();
#pragma unroll
  for (int s = 0; s < 2; ++s) {
    int chunk = tid + s * 256;
    int r8 = chunk & 7, c = chunk >> 3;
    union { unsigned short u[8]; u4 v; } pk;
#pragma unroll
    for (int i = 0; i < 8; ++i) pk.u[i] = tile[(r8 * 8 + i) * 72 + c];
    *(u4*)(dst + (size_t)(c0 + c) * R + r0 + r8 * 8) = pk.v;
  }
}

// ---------------- fused prep: x->bf16 cvt + wq/wk/wv transposes (1 launch) ----------
__global__ __launch_bounds__(256) void k_prep(
    const float* __restrict__ x, const float* __restrict__ wq,
    const float* __restrict__ wk, const float* __restrict__ wv,
    unsigned short* __restrict__ Xb, unsigned short* __restrict__ WqkvT) {
  __shared__ alignas(16) unsigned short tile[64 * 72];
  int bid = blockIdx.x;
  int tid = threadIdx.x;
  if (bid < 4096) {  // cvt: 8 f32 per thread
    int gid = bid * 256 + tid;
    const float* p = x + (size_t)gid * 8;
    f4 a = *(const f4*)p;
    f4 b = *(const f4*)(p + 4);
    union { unsigned short u[8]; u4 v; } pk;
#pragma unroll
    for (int i = 0; i < 4; ++i) { pk.u[i] = f2bf(a[i]); pk.u[4 + i] = f2bf(b[i]); }
    *(u4*)(Xb + (size_t)gid * 8) = pk.v;
  } else if (bid < 4096 + 1024) {  // wq transpose (32x32 tiles)
    int idx = bid - 4096;
    trans_tile(wq, WqkvT, 2048, 2048, (idx & 31) * 64, (idx >> 5) * 64, tid, tile);
  } else if (bid < 4096 + 1024 + 256) {  // wk (8x32 tiles)
    int idx = bid - (4096 + 1024);
    trans_tile(wk, WqkvT + (size_t)2048 * 2048, 2048, 512,
               (idx & 7) * 64, (idx >> 3) * 64, tid, tile);
  } else {  // wv
    int idx = bid - (4096 + 1024 + 256);
    trans_tile(wv, WqkvT + (size_t)2560 * 2048, 2048, 512,
               (idx & 7) * 64, (idx >> 3) * 64, tid, tile);
  }
}

// ---------------- standalone transpose (wo, runs after attn frees ws) ----------------
__global__ __launch_bounds__(256) void k_transpose_f(
    const float* __restrict__ src, unsigned short* __restrict__ dst, int R, int C) {
  __shared__ alignas(16) unsigned short tile[64 * 72];
  trans_tile(src, dst, R, C, blockIdx.x * 64, blockIdx.y * 64, threadIdx.x, tile);
}

// ================= 8-wave phase-split GEMM: C[M,N] = A[M,K] @ Bt[N,K]^T =================
#define PHASE(QM, QN, WAITC, ...)                                              \
  {                                                                            \
    wait_vmcnt<WAITC>();                                                       \
    __builtin_amdgcn_s_barrier();                                              \
    asm volatile("" ::: "memory");                                             \
    short8 af[FI][2], bf[2][2];                                                \
    _Pragma("unroll") for (int i = 0; i < FI; ++i)                             \
      _Pragma("unroll") for (int ks = 0; ks < 2; ++ks)                         \
        af[i][ks] = *(const short8*)(&As[cur][((QM) * (BM / 2) + wm * (BM / 4) + i * 16 + l16) * 64 + kswz[ks]]); \
    _Pragma("unroll") for (int j = 0; j < 2; ++j)                              \
      _Pragma("unroll") for (int ks = 0; ks < 2; ++ks)                         \
        bf[j][ks] = *(const short8*)(&Bs[cur][((QN) * 128 + wn * 32 + j * 16 + l16) * 64 + kswz[ks]]); \
    __VA_ARGS__                                                                \
    __builtin_amdgcn_s_setprio(1);                                             \
    _Pragma("unroll") for (int i = 0; i < FI; ++i)                             \
      _Pragma("unroll") for (int j = 0; j < 2; ++j)                            \
        _Pragma("unroll") for (int ks = 0; ks < 2; ++ks)                       \
          acc[(QM) * FI + i][(QN) * 2 + j] = __builtin_amdgcn_mfma_f32_16x16x32_bf16( \
              af[i][ks], bf[j][ks], acc[(QM) * FI + i][(QN) * 2 + j], 0, 0, 0); \
    __builtin_amdgcn_s_setprio(0);                                             \
  }

template <int BM, bool BF16OUT>
__global__ __launch_bounds__(512, 2) void k_gemm8(
    const unsigned short* __restrict__ A, const unsigned short* __restrict__ Bt,
    void* __restrict__ Cout, int M, int N, int K) {
  constexpr int CA = BM / 128;  // gll16 calls per A half-region
  constexpr int FI = BM / 64;   // A fragments per phase per wave
  constexpr int WA = 2 + CA, WB = 2 * CA, WC = CA + 2, PB = CA;
  __shared__ alignas(16) unsigned short As[2][BM * 64];
  __shared__ alignas(16) unsigned short Bs[2][256 * 64];
  (void)M;

  int tid = threadIdx.x;
  int wid = tid >> 6, lane = tid & 63, quad = lane >> 4, l16 = lane & 15;
  int wm = wid >> 2, wn = wid & 3;

  int nx = gridDim.x;
  int id = blockIdx.y * nx + blockIdx.x;
  int nwg = nx * gridDim.y;
  int per = nwg >> 3;
  int lin = (id & 7) * per + (id >> 3);
  int bx = lin % nx, by = lin / nx;
  int bm = by * BM, bn = bx * 256;

  int srow = lane >> 3;
  int scol = ((lane & 7) ^ srow) << 3;  // shorts
  const unsigned short* Ast = A + (size_t)(bm + wid * 8 + srow) * K + scol;
  const unsigned short* Bst = Bt + (size_t)(bn + wid * 8 + srow) * K + scol;
  const int ldsw = wid * 512;

  int kswz[2];
#pragma unroll
  for (int ks = 0; ks < 2; ++ks) kswz[ks] = (ks * 32 + quad * 8) ^ ((l16 & 7) << 3);

  f4 zero = {0.f, 0.f, 0.f, 0.f};
  f4 acc[2 * FI][4];
#pragma unroll
  for (int i = 0; i < 2 * FI; ++i)
#pragma unroll
    for (int j = 0; j < 4; ++j) acc[i][j] = zero;

  if constexpr (CA == 2) {
    gll16(Ast, &As[0][ldsw]);
    gll16(Ast + (size_t)64 * K, &As[0][ldsw + 64 * 64]);
  } else {
    gll16(Ast, &As[0][ldsw]);
  }
  gll16(Bst, &Bs[0][ldsw]);
  gll16(Bst + (size_t)64 * K, &Bs[0][ldsw + 64 * 64]);
  gll16(Bst + (size_t)128 * K, &Bs[0][ldsw + 128 * 64]);
  gll16(Bst + (size_t)192 * K, &Bs[0][ldsw + 192 * 64]);
  if constexpr (CA == 2) {
    gll16(Ast + (size_t)128 * K, &As[0][ldsw + 128 * 64]);
    gll16(Ast + (size_t)192 * K, &As[0][ldsw + 192 * 64]);
  } else {
    gll16(Ast + (size_t)64 * K, &As[0][ldsw + 64 * 64]);
  }

  int nt = K >> 6;
  int cur = 0;
  for (int t = 0; t < nt - 1; ++t) {
    int k0n = (t + 1) << 6;
    int nxt = cur ^ 1;
    unsigned short* Asn = &As[nxt][0];
    unsigned short* Bsn = &Bs[nxt][0];
    PHASE(0, 0, WA,
      if constexpr (CA == 2) {
        gll16(Ast + k0n, Asn + ldsw);
        gll16(Ast + (size_t)64 * K + k0n, Asn + ldsw + 64 * 64);
      } else {
        gll16(Ast + k0n, Asn + ldsw);
      })
    PHASE(0, 1, WB,
      gll16(Bst + k0n, Bsn + ldsw);
      gll16(Bst + (size_t)64 * K + k0n, Bsn + ldsw + 64 * 64);)
    PHASE(1, 0, WC,
      gll16(Bst + (size_t)128 * K + k0n, Bsn + ldsw + 128 * 64);
      gll16(Bst + (size_t)192 * K + k0n, Bsn + ldsw + 192 * 64);)
    PHASE(1, 1, -1,
      if constexpr (CA == 2) {
        gll16(Ast + (size_t)128 * K + k0n, Asn + ldsw + 128 * 64);
        gll16(Ast + (size_t)192 * K + k0n, Asn + ldsw + 192 * 64);
      } else {
        gll16(Ast + (size_t)64 * K + k0n, Asn + ldsw + 64 * 64);
      })
    cur = nxt;
  }
  PHASE(0, 0, WA, ;)
  PHASE(0, 1, PB, ;)
  PHASE(1, 0, 0, ;)
  PHASE(1, 1, -1, ;)

#pragma unroll
  for (int mi = 0; mi < 2 * FI; ++mi) {
    int row = bm + (mi / FI) * (BM / 2) + wm * (BM / 4) + (mi % FI) * 16 + quad * 4;
#pragma unroll
    for (int nj = 0; nj < 4; ++nj) {
      int col = bn + (nj >> 1) * 128 + wn * 32 + (nj & 1) * 16 + l16;
#pragma unroll
      for (int r = 0; r < 4; ++r) {
        if constexpr (BF16OUT)
          ((unsigned short*)Cout)[(size_t)(row + r) * N + col] = f2bf(acc[mi][nj][r]);
        else
          ((float*)Cout)[(size_t)(row + r) * N + col] = acc[mi][nj][r];
      }
    }
  }
}

// ---------------- fused RoPE (K only) + V transpose (1 launch) ----------------
// Q is roped inside k_attn (each Q row loaded exactly once there).
__global__ __launch_bounds__(256) void k_ropev(
    unsigned short* __restrict__ QKV, unsigned short* __restrict__ VT) {
  __shared__ alignas(16) unsigned short tile[64 * 72];
  int bid = blockIdx.x;
  int tid = threadIdx.x;
  if (bid < 512) {  // RoPE on K (4 heads), 8 d-pairs/thread
    int gid = bid * 256 + tid;
    int c8 = gid & 7; int g = gid >> 3;
    int h4 = g & 3; g >>= 2;
    int t = g & 2047; int b = g >> 11;
    size_t p = (size_t)(b * 2048 + t) * 3072 + 2048 + h4 * 128 + c8 * 8;
    short8 x0 = *(const short8*)(QKV + p);
    short8 x1 = *(const short8*)(QKV + p + 64);
    short8 o0, o1;
    float tf = (float)t;
#pragma unroll
    for (int i = 0; i < 8; ++i) {
      int d = c8 * 8 + i;
      float a0 = __uint_as_float((unsigned int)(unsigned short)x0[i] << 16);
      float a1 = __uint_as_float((unsigned int)(unsigned short)x1[i] << 16);
      float freq = exp2f(-(float)d * 0.20762050593046f);  // log2(10000)/64
      float ang = tf * freq;
      float cv = __cosf(ang), sv = __sinf(ang);
      o0[i] = (short)f2bf(a0 * cv - a1 * sv);
      o1[i] = (short)f2bf(a1 * cv + a0 * sv);
    }
    *(short8*)(QKV + p) = o0;
    *(short8*)(QKV + p + 64) = o1;
  } else {  // V transpose (reads V region only)
    int idx = bid - 512;            // 512 blocks
    int t0 = (idx & 31) * 64;
    int g = idx >> 5;               // b*8 + hk*2 + dh
    int dh = g & 1, hk = (g >> 1) & 3, b = g >> 3;
    int d0 = dh * 64;
    const unsigned short* src = QKV + (size_t)(b * 2048 + t0) * 3072 + 2560 + hk * 128 + d0;
#pragma unroll
    for (int s = 0; s < 2; ++s) {
      int chunk = tid + s * 256;
      int c8 = chunk & 7, r = chunk >> 3;
      *(u4*)(tile + r * 72 + c8 * 8) = *(const u4*)(src + (size_t)r * 3072 + c8 * 8);
    }
    __syncthreads();
    unsigned short* dst = VT + ((size_t)((b * 4 + hk) * 128 + d0)) * 2048 + t0;
#pragma unroll
    for (int s = 0; s < 2; ++s) {
      int chunk = tid + s * 256;
      int r8 = chunk & 7, c = chunk >> 3;
      union { unsigned short u[8]; u4 v; } pk;
#pragma unroll
      for (int i = 0; i < 8; ++i) pk.u[i] = tile[(r8 * 8 + i) * 72 + c];
      *(u4*)(dst + (size_t)c * 2048 + r8 * 8) = pk.v;
    }
  }
}

// ---------------- attention tile step: one 16q x 64k chunk for one wave ----------------
// Round-6 proven structure: pb computed and immediately consumed (short live ranges).
static __device__ __forceinline__ void attn_step(
    const unsigned short* __restrict__ Ks, const unsigned short* __restrict__ Vs,
    const short8* qf, f4* o, float& m, float& l,
    int quad, int l16, int qrow, int K0, bool mask, bool odd) {
  f4 zero = {0.f, 0.f, 0.f, 0.f};
  f4 st[4];
  __builtin_amdgcn_s_setprio(1);  // T5
#pragma unroll
  for (int kt = 0; kt < 4; ++kt) {
    st[kt] = zero;
#pragma unroll
    for (int ks = 0; ks < 4; ++ks) {
      short8 kf = *(const short8*)(Ks + (kt * 16 + l16) * 136 + ks * 32 + quad * 8);
      st[kt] = __builtin_amdgcn_mfma_f32_16x16x32_bf16(kf, qf[ks], st[kt], 0, 0, 0);
    }
  }
  __builtin_amdgcn_s_setprio(0);
  if (mask) {
#pragma unroll
    for (int kt = 0; kt < 4; ++kt)
#pragma unroll
      for (int r = 0; r < 4; ++r)
        if (K0 + kt * 16 + quad * 4 + r > qrow) st[kt][r] = -1e30f;
  }
  float sm = -1e30f;
#pragma unroll
  for (int kt = 0; kt < 4; ++kt)
#pragma unroll
    for (int r = 0; r < 4; ++r) sm = fmaxf(sm, st[kt][r]);
  sm = fmaxf(sm, __shfl_xor(sm, 16));
  sm = fmaxf(sm, __shfl_xor(sm, 32));
  // defer-max (T13): only raise m when the tile max grew past m+8.
  bool grow = !__all(sm - m <= 8.f);
  float mnew = grow ? fmaxf(m, sm) : m;
  f4 pv[4];
  float rs = 0.f;
#pragma unroll
  for (int kt = 0; kt < 4; ++kt)
#pragma unroll
    for (int r = 0; r < 4; ++r) {
      pv[kt][r] = __expf(st[kt][r] - mnew);
      rs += pv[kt][r];
    }
  rs += __shfl_xor(rs, 16);
  rs += __shfl_xor(rs, 32);
  if (grow) {
    float alpha = __expf(m - mnew);
    l = l * alpha + rs;
    m = mnew;
#pragma unroll
    for (int i = 0; i < 8; ++i) o[i] *= alpha;
  } else {
    l += rs;
  }
  unsigned int c[4][2];
#pragma unroll
  for (int kt = 0; kt < 4; ++kt)
#pragma unroll
    for (int p = 0; p < 2; ++p)
      asm("v_cvt_pk_bf16_f32 %0, %1, %2"
          : "=v"(c[kt][p]) : "v"(pv[kt][2 * p]), "v"(pv[kt][2 * p + 1]));
#pragma unroll
  for (int kh = 0; kh < 2; ++kh) {
    unsigned int A0 = c[2 * kh][0], A1 = c[2 * kh][1];
    unsigned int B0 = c[2 * kh + 1][0], B1 = c[2 * kh + 1][1];
    asm("v_permlane32_swap_b32 %0, %1" : "+v"(A0), "+v"(B0));
    asm("v_permlane32_swap_b32 %0, %1" : "+v"(A1), "+v"(B1));
    unsigned int tA0 = (unsigned int)__builtin_amdgcn_ds_swizzle((int)A0, 0x401F);
    unsigned int tA1 = (unsigned int)__builtin_amdgcn_ds_swizzle((int)A1, 0x401F);
    unsigned int tB0 = (unsigned int)__builtin_amdgcn_ds_swizzle((int)B0, 0x401F);
    unsigned int tB1 = (unsigned int)__builtin_amdgcn_ds_swizzle((int)B1, 0x401F);
    union { unsigned int u[4]; short8 s; } pb;
    pb.u[0] = odd ? tB0 : A0;
    pb.u[1] = odd ? tB1 : A1;
    pb.u[2] = odd ? B0 : tA0;
    pb.u[3] = odd ? B1 : tA1;
    __builtin_amdgcn_s_setprio(1);  // T5
#pragma unroll
    for (int i = 0; i < 8; ++i) {
      short8 vf = *(const short8*)(Vs + (i * 16 + l16) * 72 + kh * 32 + quad * 8);
      o[i] = __builtin_amdgcn_mfma_f32_16x16x32_bf16(vf, pb.s, o[i], 0, 0, 0);
    }
    __builtin_amdgcn_s_setprio(0);
  }
}

// ---------------- Flash attention: dbuf K + SINGLE-buffer V -> 53.2 KB LDS, 3 blocks/CU
// Occupancy theory: all pipes <50% busy at 2 waves/SIMD (latency-bound). Single-buffered
// Vs cuts LDS 71.7->53.2 KB => 3 blocks/CU = 3 waves/SIMD. Cost: one extra barrier/iter
// (all waves must finish PV before Vs is overwritten). Ks[nxt] writes need no barrier
// (double-buffered; reads of that buffer completed before the PREVIOUS iteration's
// trailing barrier). Q roped in-register in the prologue.
__global__ __launch_bounds__(256, 2) void k_attn(
    const unsigned short* __restrict__ QKV,  // [B*T,3072], Q raw, K roped
    const unsigned short* __restrict__ VT,   // [B,4,128,T]
    unsigned short* __restrict__ Y) {        // [B*T,2048]
  __shared__ alignas(16) unsigned short Ks[2][64 * 136];   // 34816 B (double-buffered)
  __shared__ alignas(16) unsigned short Vs[128 * 72];      // 18432 B (single buffer)
  int tid = threadIdx.x;
  int w = tid >> 6, lane = tid & 63, quad = lane >> 4, l16 = lane & 15;
  bool odd = (quad & 1) != 0;
  int bh = blockIdx.y; int b = bh >> 4, h = bh & 15, hk = h >> 2;
  int v = blockIdx.x;                 // 0..15
  int q0A = v * 64 + w * 16;          // early tile
  int q0B = (31 - v) * 64 + w * 16;   // late tile
  const unsigned short* Qh = QKV + (size_t)b * 2048 * 3072 + h * 128;
  const unsigned short* Kh = QKV + (size_t)b * 2048 * 3072 + 2048 + hk * 128;
  const unsigned short* Vh = VT + ((size_t)(b * 4 + hk) * 128) * 2048;

  int rK0 = tid >> 4, cK = tid & 15;
  int rV0 = tid >> 3, cV = tid & 7;

  short8 qfA[4], qfB[4];
#pragma unroll
  for (int ks = 0; ks < 4; ++ks) {
    qfA[ks] = *(const short8*)(Qh + (size_t)(q0A + l16) * 3072 + ks * 32 + quad * 8);
    qfB[ks] = *(const short8*)(Qh + (size_t)(q0B + l16) * 3072 + ks * 32 + quad * 8);
  }
  // in-register Q RoPE + 1/sqrt(128) scale; qf[ks][i] holds d = ks*32+quad*8+i,
  // partner d+64 is qf[ks+2][i] (same lane).
#pragma unroll
  for (int tix = 0; tix < 2; ++tix) {
    short8* qf = tix ? qfB : qfA;
    float tf = (float)((tix ? q0B : q0A) + l16);
#pragma unroll
    for (int ks = 0; ks < 2; ++ks)
#pragma unroll
      for (int i = 0; i < 8; ++i) {
        int d = ks * 32 + quad * 8 + i;
        float x0 = __uint_as_float((unsigned int)(unsigned short)qf[ks][i] << 16);
        float x1 = __uint_as_float((unsigned int)(unsigned short)qf[ks + 2][i] << 16);
        float freq = exp2f(-(float)d * 0.20762050593046f);  // log2(10000)/64
        float ang = tf * freq;
        float cv = __cosf(ang), sv = __sinf(ang);
        qf[ks][i] = (short)f2bf((x0 * cv - x1 * sv) * 0.088388347648318f);
        qf[ks + 2][i] = (short)f2bf((x1 * cv + x0 * sv) * 0.088388347648318f);
      }
  }

  f4 zero = {0.f, 0.f, 0.f, 0.f};
  f4 oA[8], oB[8];
#pragma unroll
  for (int i = 0; i < 8; ++i) { oA[i] = zero; oB[i] = zero; }
  float mA = -1e30f, lA = 0.f, mB = -1e30f, lB = 0.f;

  int nch = 32 - v;  // chunks 0..31-v (tile B's causal range)

#pragma unroll
  for (int s = 0; s < 4; ++s) {
    int rK = rK0 + 16 * s;
    *(u4*)(&Ks[0][0] + rK * 136 + cK * 8) =
        *(const u4*)(Kh + (size_t)rK * 3072 + cK * 8);
    int rV = rV0 + 32 * s;
    *(u4*)(Vs + rV * 72 + cV * 8) =
        *(const u4*)(Vh + (size_t)rV * 2048 + cV * 8);
  }
  __syncthreads();

  for (int kc = 0; kc < nch; ++kc) {
    int cur = kc & 1, nxt = cur ^ 1;
    int K0 = kc * 64;
    bool have_next = (kc + 1) < nch;
    u4 kreg[4], vreg[4];
    if (have_next) {  // issue next-chunk loads before compute (latency overlap)
      int K0n = K0 + 64;
#pragma unroll
      for (int s = 0; s < 4; ++s) {
        int rK = rK0 + 16 * s;
        kreg[s] = *(const u4*)(Kh + (size_t)(K0n + rK) * 3072 + cK * 8);
        int rV = rV0 + 32 * s;
        vreg[s] = *(const u4*)(Vh + (size_t)rV * 2048 + K0n + cV * 8);
      }
    }

    if (kc <= v)  // block-uniform branch
      attn_step(&Ks[cur][0], Vs, qfA, oA, mA, lA, quad, l16, q0A + l16, K0, kc == v, odd);
    attn_step(&Ks[cur][0], Vs, qfB, oB, mB, lB, quad, l16, q0B + l16, K0, kc == nch - 1, odd);

    if (have_next) {
      // Ks[nxt] is double-buffered: its last readers finished before the previous
      // iteration's trailing barrier -> safe to write now (overlaps other waves' PV).
#pragma unroll
      for (int s = 0; s < 4; ++s) {
        int rK = rK0 + 16 * s;
        *(u4*)(&Ks[nxt][0] + rK * 136 + cK * 8) = kreg[s];
      }
      __syncthreads();  // all waves done reading Vs (chunk kc)
#pragma unroll
      for (int s = 0; s < 4; ++s) {
        int rV = rV0 + 32 * s;
        *(u4*)(Vs + rV * 72 + cV * 8) = vreg[s];
      }
    }
    __syncthreads();
  }

  float rA = 1.f / lA, rB = 1.f / lB;
  size_t yrowA = (size_t)(b * 2048 + q0A + l16) * 2048 + h * 128;
  size_t yrowB = (size_t)(b * 2048 + q0B + l16) * 2048 + h * 128;
#pragma unroll
  for (int i = 0; i < 8; ++i)
#pragma unroll
    for (int r = 0; r < 4; ++r) {
      Y[yrowA + i * 16 + quad * 4 + r] = f2bf(oA[i][r] * rA);
      Y[yrowB + i * 16 + quad * 4 + r] = f2bf(oB[i][r] * rB);
    }
}

extern "C" void kernel_launch(void* const* d_in, const int* in_sizes, int n_in,
                              void* d_out, int out_size, void* d_ws, size_t ws_size,
                              hipStream_t stream) {
  const float* x  = (const float*)d_in[0];   // [2,2048,2048] fp32
  const float* wq = (const float*)d_in[1];   // [2048,2048]
  const float* wk = (const float*)d_in[2];   // [2048,512]
  const float* wv = (const float*)d_in[3];   // [2048,512]
  const float* wo = (const float*)d_in[4];   // [2048,2048]
  float* outp = (float*)d_out;               // [2,2048,2048] fp32

  unsigned short* WqkvT = (unsigned short*)d_out;
  unsigned short* VT    = WqkvT + (size_t)3072 * 2048;
  unsigned short* Xb    = VT + (size_t)2 * 4 * 128 * 2048;
  unsigned short* QKV = (unsigned short*)d_ws;               // [4096][3072]
  unsigned short* Yb  = QKV + (size_t)4096 * 3072;           // [4096][2048]
  unsigned short* WoT = QKV;

  dim3 blk(256);
  k_prep<<<dim3(5632), blk, 0, stream>>>(x, wq, wk, wv, Xb, WqkvT);

  k_gemm8<256, true><<<dim3(12, 16), dim3(512), 0, stream>>>(
      Xb, WqkvT, QKV, 4096, 3072, 2048);

  k_ropev<<<dim3(1024), blk, 0, stream>>>(QKV, VT);

  k_attn<<<dim3(16, 32), blk, 0, stream>>>(QKV, VT, Yb);

  k_transpose_f<<<dim3(32, 32), blk, 0, stream>>>(wo, WoT, 2048, 2048);
  k_gemm8<128, false><<<dim3(8, 32), dim3(512), 0, stream>>>(
      Yb, WoT, outp, 4096, 2048, 2048);
}